// Round 1
// baseline (1288.922 us; speedup 1.0000x reference)
//
#include <hip/hip_runtime.h>
#include <hip/hip_bf16.h>

// Problem constants
#define BATCH   2
#define LSEQ    2048
#define DMODEL  1024
#define DINNER  2048
#define NST     16
#define KCONV   4

// ---------------------------------------------------------------------------
// Generic NT GEMM: C[m][n] = sum_k A[m][k] * B[n][k]   (both row-major, K fast)
// BM=BN=128, BK=16, 256 threads, 8x8 micro-tile per thread (split 4+4 regions)
// ---------------------------------------------------------------------------
template<int M, int N, int K>
__global__ __launch_bounds__(256, 2) void gemm_nt(const float* __restrict__ A,
                                                  const float* __restrict__ Bm,
                                                  float* __restrict__ C) {
  constexpr int BK  = 16;
  constexpr int LDT = 128 + 4;  // pad 4 floats: keeps 16B alignment, rotates banks
  __shared__ float As[BK][LDT];
  __shared__ float Bs[BK][LDT];
  const int tid  = threadIdx.x;
  const int tx   = tid & 15;   // col group 0..15
  const int ty   = tid >> 4;   // row group 0..15
  const int row0 = blockIdx.y * 128;
  const int col0 = blockIdx.x * 128;
  float acc[8][8] = {};

  for (int k0 = 0; k0 < K; k0 += BK) {
    // Stage 128x16 tiles of A and B, float4 per load (2 float4 each per thread)
    #pragma unroll
    for (int i = 0; i < 2; ++i) {
      int idx = tid + i * 256;       // 0..511
      int r   = idx >> 2;            // 0..127
      int c4  = (idx & 3) << 2;      // 0,4,8,12
      float4 av = *(const float4*)(A  + (size_t)(row0 + r) * K + k0 + c4);
      As[c4 + 0][r] = av.x; As[c4 + 1][r] = av.y;
      As[c4 + 2][r] = av.z; As[c4 + 3][r] = av.w;
      float4 bv = *(const float4*)(Bm + (size_t)(col0 + r) * K + k0 + c4);
      Bs[c4 + 0][r] = bv.x; Bs[c4 + 1][r] = bv.y;
      Bs[c4 + 2][r] = bv.z; Bs[c4 + 3][r] = bv.w;
    }
    __syncthreads();
    #pragma unroll
    for (int kk = 0; kk < BK; ++kk) {
      float4 a0 = *(const float4*)&As[kk][ty * 4];
      float4 a1 = *(const float4*)&As[kk][64 + ty * 4];
      float4 b0 = *(const float4*)&Bs[kk][tx * 4];
      float4 b1 = *(const float4*)&Bs[kk][64 + tx * 4];
      float a[8] = {a0.x, a0.y, a0.z, a0.w, a1.x, a1.y, a1.z, a1.w};
      float b[8] = {b0.x, b0.y, b0.z, b0.w, b1.x, b1.y, b1.z, b1.w};
      #pragma unroll
      for (int i = 0; i < 8; ++i)
        #pragma unroll
        for (int j = 0; j < 8; ++j)
          acc[i][j] += a[i] * b[j];
    }
    __syncthreads();
  }

  #pragma unroll
  for (int i = 0; i < 8; ++i) {
    int r = (i < 4) ? (ty * 4 + i) : (64 + ty * 4 + (i - 4));
    float4 v0 = make_float4(acc[i][0], acc[i][1], acc[i][2], acc[i][3]);
    float4 v1 = make_float4(acc[i][4], acc[i][5], acc[i][6], acc[i][7]);
    *(float4*)(C + (size_t)(row0 + r) * N + col0 + tx * 4)      = v0;
    *(float4*)(C + (size_t)(row0 + r) * N + col0 + 64 + tx * 4) = v1;
  }
}

// ---------------------------------------------------------------------------
// Causal depthwise conv1d(K=4) + bias + SiLU.  xi = first half of xz rows.
// One thread per (b,t,d).
// ---------------------------------------------------------------------------
__global__ __launch_bounds__(256) void conv_kernel(const float* __restrict__ xz,
                                                   const float* __restrict__ cw,
                                                   const float* __restrict__ cb,
                                                   float* __restrict__ u) {
  size_t idx = (size_t)blockIdx.x * 256 + threadIdx.x;  // B*L*DINNER
  int d = (int)(idx & (DINNER - 1));
  int t = (int)((idx >> 11) & (LSEQ - 1));
  int b = (int)(idx >> 22);
  const float4 w = *(const float4*)(cw + d * 4);
  float s = cb[d];
  size_t base = ((size_t)b * LSEQ + t) * (2 * DINNER) + d;
  if (t >= 3) s += w.x * xz[base - 3 * (size_t)(2 * DINNER)];
  if (t >= 2) s += w.y * xz[base - 2 * (size_t)(2 * DINNER)];
  if (t >= 1) s += w.z * xz[base - 1 * (size_t)(2 * DINNER)];
  s += w.w * xz[base];
  // SiLU
  float v = s / (1.0f + __expf(-s));
  u[idx] = v;
}

// ---------------------------------------------------------------------------
// x_dbl = u · W_xᵀ  (33 outputs per (b,t) row), then:
//   bc[row][0..15]  = B,  bc[row][16..31] = C
//   delta row written into the (dead) xi half of xz: softplus(dlt*W_dt + b_dt)
// One block per (b,t) row, 256 threads.
// ---------------------------------------------------------------------------
__global__ __launch_bounds__(256) void xdbl_kernel(const float* __restrict__ u,
                                                   const float* __restrict__ Wx,
                                                   const float* __restrict__ Wdt,
                                                   const float* __restrict__ bdt,
                                                   float* __restrict__ xz,
                                                   float* __restrict__ bc) {
  const int row = blockIdx.x;        // b*L + t  (0..4095)
  const int tid = threadIdx.x;
  __shared__ float sred[4][33];
  __shared__ float sdlt;

  float acc[33];
  #pragma unroll
  for (int e = 0; e < 33; ++e) acc[e] = 0.0f;

  const float* urow = u + (size_t)row * DINNER;
  for (int k = tid; k < DINNER; k += 256) {
    float uk = urow[k];
    #pragma unroll
    for (int e = 0; e < 33; ++e)
      acc[e] += uk * Wx[e * DINNER + k];
  }
  // wave (64-lane) butterfly reduce for each of 33 partials
  #pragma unroll
  for (int e = 0; e < 33; ++e) {
    #pragma unroll
    for (int m = 1; m < 64; m <<= 1)
      acc[e] += __shfl_xor(acc[e], m);
  }
  if ((tid & 63) == 0) {
    #pragma unroll
    for (int e = 0; e < 33; ++e) sred[tid >> 6][e] = acc[e];
  }
  __syncthreads();
  if (tid < 33) {
    float v = sred[0][tid] + sred[1][tid] + sred[2][tid] + sred[3][tid];
    if (tid == 0) sdlt = v;
    else          bc[(size_t)row * 32 + (tid - 1)] = v;
  }
  __syncthreads();
  const float dlt = sdlt;
  for (int d = tid; d < DINNER; d += 256) {
    float xarg = dlt * Wdt[d] + bdt[d];
    // stable softplus
    float sp = fmaxf(xarg, 0.0f) + log1pf(__expf(-fabsf(xarg)));
    xz[(size_t)row * (2 * DINNER) + d] = sp;
  }
}

// ---------------------------------------------------------------------------
// Selective scan. Block = 16 channels (b, d0..d0+15), 16 lanes per channel
// (one per state n). LDS double-buffered chunks of 64 timesteps.
// Fuses SiLU(z) gate; writes y in place over u.
// ---------------------------------------------------------------------------
__global__ __launch_bounds__(256) void scan_kernel(float* __restrict__ u,      // (B,L,D) in, y out (in place)
                                                   const float* __restrict__ xz, // delta in xi half, z in z half
                                                   const float* __restrict__ bc, // (B*L,32)
                                                   const float* __restrict__ Amat) {
  constexpr int TCH = 64;
  constexpr int NC  = LSEQ / TCH;
  __shared__ float su [2][TCH][16];
  __shared__ float sdl[2][TCH][16];
  __shared__ float szg[2][TCH][16];
  __shared__ float sbc[2][TCH][32];

  const int tid = threadIdx.x;
  const int g   = tid >> 4;   // channel within block 0..15
  const int n   = tid & 15;   // state index
  const int gc  = blockIdx.x * 16 + g;        // global channel (b,d)
  const int b   = gc >> 11;                    // /2048
  const int d   = gc & (DINNER - 1);
  const int d0  = (blockIdx.x * 16) & (DINNER - 1);
  const int bb  = (blockIdx.x * 16) >> 11;

  const float A_dn = Amat[d * NST + n];
  float h = 0.0f;

  auto stage = [&](int c, int sb) {
    const int t0 = c * TCH;
    #pragma unroll
    for (int i = 0; i < 4; ++i) {
      int idx = tid + i * 256;
      int tt = idx >> 4, dd = idx & 15;
      size_t grow = (size_t)bb * LSEQ + t0 + tt;
      su [sb][tt][dd] = u [grow * DINNER + d0 + dd];
      sdl[sb][tt][dd] = xz[grow * (2 * DINNER) + d0 + dd];
      szg[sb][tt][dd] = xz[grow * (2 * DINNER) + DINNER + d0 + dd];
    }
    #pragma unroll
    for (int i = 0; i < 8; ++i) {
      int idx = tid + i * 256;
      int tt = idx >> 5, e = idx & 31;
      sbc[sb][tt][e] = bc[((size_t)bb * LSEQ + t0 + tt) * 32 + e];
    }
  };

  stage(0, 0);
  for (int c = 0; c < NC; ++c) {
    __syncthreads();
    if (c + 1 < NC) stage(c + 1, (c + 1) & 1);
    const int sb = c & 1;
    #pragma unroll 4
    for (int tt = 0; tt < TCH; ++tt) {
      float u_t = su [sb][tt][g];
      float dl  = sdl[sb][tt][g];
      float z_t = szg[sb][tt][g];
      float Bn  = sbc[sb][tt][n];
      float Cn  = sbc[sb][tt][16 + n];
      float ab  = __expf(dl * A_dn);
      h = ab * h + (dl * u_t) * Bn;
      float p = h * Cn;
      p += __shfl_xor(p, 1);
      p += __shfl_xor(p, 2);
      p += __shfl_xor(p, 4);
      p += __shfl_xor(p, 8);
      if (n == 0) {
        float sig = 1.0f / (1.0f + __expf(-z_t));
        u[((size_t)b * LSEQ + c * TCH + tt) * DINNER + d] = p * z_t * sig;
      }
    }
  }
}

// ---------------------------------------------------------------------------
extern "C" void kernel_launch(void* const* d_in, const int* in_sizes, int n_in,
                              void* d_out, int out_size, void* d_ws, size_t ws_size,
                              hipStream_t stream) {
  const float* x      = (const float*)d_in[0];
  const float* W_in   = (const float*)d_in[1];
  const float* conv_w = (const float*)d_in[2];
  const float* conv_b = (const float*)d_in[3];
  const float* A      = (const float*)d_in[4];
  const float* W_x    = (const float*)d_in[5];
  const float* W_dt   = (const float*)d_in[6];
  const float* b_dt   = (const float*)d_in[7];
  const float* W_out  = (const float*)d_in[8];
  float* out = (float*)d_out;

  float* ws = (float*)d_ws;
  float* xz = ws;                                   // (B*L, 4096)  64 MB
  float* u  = ws + (size_t)BATCH * LSEQ * 2 * DINNER;   // (B*L, 2048)  32 MB
  float* bc = u  + (size_t)BATCH * LSEQ * DINNER;       // (B*L, 32)   0.5 MB

  const int ML = BATCH * LSEQ;  // 4096

  // 1) in_proj
  gemm_nt<ML, 2 * DINNER, DMODEL><<<dim3((2 * DINNER) / 128, ML / 128), 256, 0, stream>>>(x, W_in, xz);
  // 2) conv + silu
  conv_kernel<<<(ML * DINNER) / 256, 256, 0, stream>>>(xz, conv_w, conv_b, u);
  // 3) x_dbl (B,C into bc; softplus-delta into xi half of xz)
  xdbl_kernel<<<ML, 256, 0, stream>>>(u, W_x, W_dt, b_dt, xz, bc);
  // 4) selective scan + gate (y in place over u)
  scan_kernel<<<(BATCH * DINNER) / 16, 256, 0, stream>>>(u, xz, bc, A);
  // 5) out_proj
  gemm_nt<ML, DMODEL, DINNER><<<dim3(DMODEL / 128, ML / 128), 256, 0, stream>>>(u, W_out, out);
}

// Round 2
// 875.850 us; speedup vs baseline: 1.4716x; 1.4716x over previous
//
#include <hip/hip_runtime.h>
#include <hip/hip_bf16.h>

// Problem constants
#define BATCH   2
#define LSEQ    2048
#define DMODEL  1024
#define DINNER  2048
#define NST     16
#define KCONV   4

// Chunked scan parameters
#define LC      64
#define NCHUNK  (LSEQ / LC)   // 32

// ---------------------------------------------------------------------------
// Generic NT GEMM: C[m][n] = sum_k A[m][k] * B[n][k]   (both row-major, K fast)
// ---------------------------------------------------------------------------
template<int M, int N, int K>
__global__ __launch_bounds__(256, 2) void gemm_nt(const float* __restrict__ A,
                                                  const float* __restrict__ Bm,
                                                  float* __restrict__ C) {
  constexpr int BK  = 16;
  constexpr int LDT = 128 + 4;
  __shared__ float As[BK][LDT];
  __shared__ float Bs[BK][LDT];
  const int tid  = threadIdx.x;
  const int tx   = tid & 15;
  const int ty   = tid >> 4;
  const int row0 = blockIdx.y * 128;
  const int col0 = blockIdx.x * 128;
  float acc[8][8] = {};

  for (int k0 = 0; k0 < K; k0 += BK) {
    #pragma unroll
    for (int i = 0; i < 2; ++i) {
      int idx = tid + i * 256;
      int r   = idx >> 2;
      int c4  = (idx & 3) << 2;
      float4 av = *(const float4*)(A  + (size_t)(row0 + r) * K + k0 + c4);
      As[c4 + 0][r] = av.x; As[c4 + 1][r] = av.y;
      As[c4 + 2][r] = av.z; As[c4 + 3][r] = av.w;
      float4 bv = *(const float4*)(Bm + (size_t)(col0 + r) * K + k0 + c4);
      Bs[c4 + 0][r] = bv.x; Bs[c4 + 1][r] = bv.y;
      Bs[c4 + 2][r] = bv.z; Bs[c4 + 3][r] = bv.w;
    }
    __syncthreads();
    #pragma unroll
    for (int kk = 0; kk < BK; ++kk) {
      float4 a0 = *(const float4*)&As[kk][ty * 4];
      float4 a1 = *(const float4*)&As[kk][64 + ty * 4];
      float4 b0 = *(const float4*)&Bs[kk][tx * 4];
      float4 b1 = *(const float4*)&Bs[kk][64 + tx * 4];
      float a[8] = {a0.x, a0.y, a0.z, a0.w, a1.x, a1.y, a1.z, a1.w};
      float b[8] = {b0.x, b0.y, b0.z, b0.w, b1.x, b1.y, b1.z, b1.w};
      #pragma unroll
      for (int i = 0; i < 8; ++i)
        #pragma unroll
        for (int j = 0; j < 8; ++j)
          acc[i][j] += a[i] * b[j];
    }
    __syncthreads();
  }

  #pragma unroll
  for (int i = 0; i < 8; ++i) {
    int r = (i < 4) ? (ty * 4 + i) : (64 + ty * 4 + (i - 4));
    float4 v0 = make_float4(acc[i][0], acc[i][1], acc[i][2], acc[i][3]);
    float4 v1 = make_float4(acc[i][4], acc[i][5], acc[i][6], acc[i][7]);
    *(float4*)(C + (size_t)(row0 + r) * N + col0 + tx * 4)      = v0;
    *(float4*)(C + (size_t)(row0 + r) * N + col0 + 64 + tx * 4) = v1;
  }
}

// ---------------------------------------------------------------------------
// Causal depthwise conv1d(K=4) + bias + SiLU.
// ---------------------------------------------------------------------------
__global__ __launch_bounds__(256) void conv_kernel(const float* __restrict__ xz,
                                                   const float* __restrict__ cw,
                                                   const float* __restrict__ cb,
                                                   float* __restrict__ u) {
  size_t idx = (size_t)blockIdx.x * 256 + threadIdx.x;
  int d = (int)(idx & (DINNER - 1));
  int t = (int)((idx >> 11) & (LSEQ - 1));
  const float4 w = *(const float4*)(cw + d * 4);
  float s = cb[d];
  size_t base = idx * 2 - (size_t)d;  // ((b*L+t)*2*DINNER + d)
  // note: idx = (b*L+t)*DINNER + d  ->  row*2*DINNER + d = idx*2 - d
  if (t >= 3) s += w.x * xz[base - 3 * (size_t)(2 * DINNER)];
  if (t >= 2) s += w.y * xz[base - 2 * (size_t)(2 * DINNER)];
  if (t >= 1) s += w.z * xz[base - 1 * (size_t)(2 * DINNER)];
  s += w.w * xz[base];
  float v = s / (1.0f + __expf(-s));
  u[idx] = v;
}

// ---------------------------------------------------------------------------
// x_dbl per (b,t) row: B,C -> bc; softplus-delta -> xi half of xz.
// ---------------------------------------------------------------------------
__global__ __launch_bounds__(256) void xdbl_kernel(const float* __restrict__ u,
                                                   const float* __restrict__ Wx,
                                                   const float* __restrict__ Wdt,
                                                   const float* __restrict__ bdt,
                                                   float* __restrict__ xz,
                                                   float* __restrict__ bc) {
  const int row = blockIdx.x;
  const int tid = threadIdx.x;
  __shared__ float sred[4][33];
  __shared__ float sdlt;

  float acc[33];
  #pragma unroll
  for (int e = 0; e < 33; ++e) acc[e] = 0.0f;

  const float* urow = u + (size_t)row * DINNER;
  for (int k = tid; k < DINNER; k += 256) {
    float uk = urow[k];
    #pragma unroll
    for (int e = 0; e < 33; ++e)
      acc[e] += uk * Wx[e * DINNER + k];
  }
  #pragma unroll
  for (int e = 0; e < 33; ++e) {
    #pragma unroll
    for (int m = 1; m < 64; m <<= 1)
      acc[e] += __shfl_xor(acc[e], m);
  }
  if ((tid & 63) == 0) {
    #pragma unroll
    for (int e = 0; e < 33; ++e) sred[tid >> 6][e] = acc[e];
  }
  __syncthreads();
  if (tid < 33) {
    float v = sred[0][tid] + sred[1][tid] + sred[2][tid] + sred[3][tid];
    if (tid == 0) sdlt = v;
    else          bc[(size_t)row * 32 + (tid - 1)] = v;
  }
  __syncthreads();
  const float dlt = sdlt;
  for (int d = tid; d < DINNER; d += 256) {
    float xarg = dlt * Wdt[d] + bdt[d];
    float sp = fmaxf(xarg, 0.0f) + log1pf(__expf(-fabsf(xarg)));
    xz[(size_t)row * (2 * DINNER) + d] = sp;
  }
}

// ---------------------------------------------------------------------------
// Chunked parallel scan, phase A: per (channel-group, chunk) block, scan the
// chunk from h=0 and emit P = prod(a_t), W = h_end.
// Layout of P/W: [gc][c][n]  ->  ((gc*NCHUNK)+c)*16 + n
// ---------------------------------------------------------------------------
__global__ __launch_bounds__(256) void scanA(const float* __restrict__ u,
                                             const float* __restrict__ xz,
                                             const float* __restrict__ bc,
                                             const float* __restrict__ Amat,
                                             float* __restrict__ Pbuf,
                                             float* __restrict__ Wbuf) {
  __shared__ float su [LC][16];
  __shared__ float sdl[LC][16];
  __shared__ float sB [LC][16];
  const int tid = threadIdx.x;
  const int c   = blockIdx.x & (NCHUNK - 1);
  const int cg  = blockIdx.x >> 5;           // channel group 0..255
  const int g   = tid >> 4;
  const int n   = tid & 15;
  const int gc  = cg * 16 + g;
  const int d   = gc & (DINNER - 1);
  const int d0  = (cg * 16) & (DINNER - 1);
  const int bb  = (cg * 16) >> 11;
  const int t0  = c * LC;

  #pragma unroll
  for (int i = 0; i < 4; ++i) {
    int idx = tid + i * 256;
    int tt = idx >> 4, dd = idx & 15;
    size_t grow = (size_t)bb * LSEQ + t0 + tt;
    su [tt][dd] = u [grow * DINNER + d0 + dd];
    sdl[tt][dd] = xz[grow * (2 * DINNER) + d0 + dd];
    sB [tt][dd] = bc[grow * 32 + dd];
  }
  __syncthreads();

  const float A_dn = Amat[d * NST + n];
  float P = 1.0f, h = 0.0f;
  #pragma unroll 8
  for (int tt = 0; tt < LC; ++tt) {
    float dl = sdl[tt][g];
    float uu = su [tt][g];
    float Bn = sB [tt][n];
    float ab = __expf(dl * A_dn);
    h = ab * h + (dl * uu) * Bn;
    P *= ab;
  }
  size_t o = ((size_t)gc * NCHUNK + c) * 16 + n;
  Pbuf[o] = P;
  Wbuf[o] = h;
}

// ---------------------------------------------------------------------------
// Phase B: per (b,d,n) lane, combine the 32 chunk summaries serially in
// registers; write chunk-entry states Hin in place over Pbuf.
// ---------------------------------------------------------------------------
__global__ __launch_bounds__(256) void scanB(float* __restrict__ Pbuf,
                                             const float* __restrict__ Wbuf) {
  const int lane_id = blockIdx.x * 256 + threadIdx.x;  // (b,d,n) flat
  const int gc = lane_id >> 4;
  const int n  = lane_id & 15;
  const size_t base = (size_t)gc * NCHUNK * 16 + n;
  float P[NCHUNK], W[NCHUNK];
  #pragma unroll
  for (int c = 0; c < NCHUNK; ++c) {
    P[c] = Pbuf[base + (size_t)c * 16];
    W[c] = Wbuf[base + (size_t)c * 16];
  }
  float h = 0.0f;
  #pragma unroll
  for (int c = 0; c < NCHUNK; ++c) {
    float hin = h;
    h = P[c] * h + W[c];
    Pbuf[base + (size_t)c * 16] = hin;   // Hin for chunk c
  }
}

// ---------------------------------------------------------------------------
// Phase C: per (channel-group, chunk) block, start from Hin, rescan the
// chunk, reduce over n, apply SiLU(z) gate, write y over u.
// ---------------------------------------------------------------------------
__global__ __launch_bounds__(256) void scanC(float* __restrict__ u,
                                             const float* __restrict__ xz,
                                             const float* __restrict__ bc,
                                             const float* __restrict__ Amat,
                                             const float* __restrict__ Hin) {
  __shared__ float su [LC][16];
  __shared__ float sdl[LC][16];
  __shared__ float szg[LC][16];
  __shared__ float sB [LC][16];
  __shared__ float sC [LC][16];
  const int tid = threadIdx.x;
  const int c   = blockIdx.x & (NCHUNK - 1);
  const int cg  = blockIdx.x >> 5;
  const int g   = tid >> 4;
  const int n   = tid & 15;
  const int gc  = cg * 16 + g;
  const int d   = gc & (DINNER - 1);
  const int d0  = (cg * 16) & (DINNER - 1);
  const int bb  = (cg * 16) >> 11;
  const int t0  = c * LC;

  #pragma unroll
  for (int i = 0; i < 4; ++i) {
    int idx = tid + i * 256;
    int tt = idx >> 4, dd = idx & 15;
    size_t grow = (size_t)bb * LSEQ + t0 + tt;
    su [tt][dd] = u [grow * DINNER + d0 + dd];
    sdl[tt][dd] = xz[grow * (2 * DINNER) + d0 + dd];
    szg[tt][dd] = xz[grow * (2 * DINNER) + DINNER + d0 + dd];
  }
  #pragma unroll
  for (int i = 0; i < 8; ++i) {
    int idx = tid + i * 256;
    int tt = idx >> 5, e = idx & 31;
    float v = bc[((size_t)bb * LSEQ + t0 + tt) * 32 + e];
    if (e < 16) sB[tt][e] = v;
    else        sC[tt][e - 16] = v;
  }
  __syncthreads();

  const float A_dn = Amat[d * NST + n];
  float h = Hin[((size_t)gc * NCHUNK + c) * 16 + n];
  #pragma unroll 8
  for (int tt = 0; tt < LC; ++tt) {
    float dl = sdl[tt][g];
    float uu = su [tt][g];
    float zt = szg[tt][g];
    float Bn = sB [tt][n];
    float Cn = sC [tt][n];
    float ab = __expf(dl * A_dn);
    h = ab * h + (dl * uu) * Bn;
    float p = h * Cn;
    p += __shfl_xor(p, 1);
    p += __shfl_xor(p, 2);
    p += __shfl_xor(p, 4);
    p += __shfl_xor(p, 8);
    if (n == 0) {
      float sig = 1.0f / (1.0f + __expf(-zt));
      u[((size_t)bb * LSEQ + t0 + tt) * DINNER + d] = p * zt * sig;
    }
  }
}

// ---------------------------------------------------------------------------
extern "C" void kernel_launch(void* const* d_in, const int* in_sizes, int n_in,
                              void* d_out, int out_size, void* d_ws, size_t ws_size,
                              hipStream_t stream) {
  const float* x      = (const float*)d_in[0];
  const float* W_in   = (const float*)d_in[1];
  const float* conv_w = (const float*)d_in[2];
  const float* conv_b = (const float*)d_in[3];
  const float* A      = (const float*)d_in[4];
  const float* W_x    = (const float*)d_in[5];
  const float* W_dt   = (const float*)d_in[6];
  const float* b_dt   = (const float*)d_in[7];
  const float* W_out  = (const float*)d_in[8];
  float* out = (float*)d_out;

  float* ws = (float*)d_ws;
  float* xz = ws;                                        // (B*L, 4096)   64 MB
  float* u  = xz + (size_t)BATCH * LSEQ * 2 * DINNER;    // (B*L, 2048)   32 MB
  float* bc = u  + (size_t)BATCH * LSEQ * DINNER;        // (B*L, 32)    0.5 MB
  float* Pb = bc + (size_t)BATCH * LSEQ * 32;            // (B*D, NC, 16)  8 MB
  float* Wb = Pb + (size_t)BATCH * DINNER * NCHUNK * 16; // (B*D, NC, 16)  8 MB

  const int ML = BATCH * LSEQ;  // 4096

  // 1) in_proj
  gemm_nt<ML, 2 * DINNER, DMODEL><<<dim3((2 * DINNER) / 128, ML / 128), 256, 0, stream>>>(x, W_in, xz);
  // 2) conv + silu
  conv_kernel<<<(ML * DINNER) / 256, 256, 0, stream>>>(xz, conv_w, conv_b, u);
  // 3) x_dbl
  xdbl_kernel<<<ML, 256, 0, stream>>>(u, W_x, W_dt, b_dt, xz, bc);
  // 4) chunked selective scan
  scanA<<<(BATCH * DINNER / 16) * NCHUNK, 256, 0, stream>>>(u, xz, bc, A, Pb, Wb);
  scanB<<<(BATCH * DINNER * NST) / 256, 256, 0, stream>>>(Pb, Wb);
  scanC<<<(BATCH * DINNER / 16) * NCHUNK, 256, 0, stream>>>(u, xz, bc, A, Pb);
  // 5) out_proj
  gemm_nt<ML, DMODEL, DINNER><<<dim3(DMODEL / 128, ML / 128), 256, 0, stream>>>(u, W_out, out);
}

// Round 3
// 377.384 us; speedup vs baseline: 3.4154x; 2.3208x over previous
//
#include <hip/hip_runtime.h>
#include <hip/hip_bf16.h>

// Problem constants
#define BATCH   2
#define LSEQ    2048
#define DMODEL  1024
#define DINNER  2048
#define NST     16

// Chunked scan parameters
#define LC      64
#define NCHUNK  (LSEQ / LC)   // 32

typedef __bf16 bf16x8 __attribute__((ext_vector_type(8)));
typedef float  f32x4  __attribute__((ext_vector_type(4)));

// float -> bf16 round-to-nearest-even (inputs are finite; skip NaN path)
__device__ __forceinline__ unsigned short f2bf(float f) {
  unsigned int u = __float_as_uint(f);
  return (unsigned short)((u + 0x7FFFu + ((u >> 16) & 1u)) >> 16);
}

__device__ __forceinline__ void async_copy16(const void* g, void* l) {
  __builtin_amdgcn_global_load_lds((__attribute__((address_space(1))) void*)g,
                                   (__attribute__((address_space(3))) void*)l,
                                   16, 0, 0);
}

// ---------------------------------------------------------------------------
// f32 -> bf16 conversion, 4 elements/thread
// ---------------------------------------------------------------------------
__global__ __launch_bounds__(256) void cvt_bf16(const float4* __restrict__ in,
                                                ushort4* __restrict__ o, int n4) {
  int i = blockIdx.x * 256 + threadIdx.x;
  if (i >= n4) return;
  float4 v = in[i];
  ushort4 r;
  r.x = f2bf(v.x); r.y = f2bf(v.y); r.z = f2bf(v.z); r.w = f2bf(v.w);
  o[i] = r;
}

// ---------------------------------------------------------------------------
// bf16 NT GEMM (m97 structure): C[m][n] = sum_k A[m][k]*B[n][k], C fp32.
// 128x128 tile, BK=32, 4 waves (2x2 of 64x64), global_load_lds width 16.
// ---------------------------------------------------------------------------
template<int N, int K>
__global__ __launch_bounds__(256, 2) void gemm_bf16(const unsigned short* __restrict__ A,
                                                    const unsigned short* __restrict__ B,
                                                    float* __restrict__ C) {
  __shared__ unsigned short As[128][32];   // 8 KB, row = 64 B
  __shared__ unsigned short Bs[128][32];
  const int tid  = threadIdx.x;
  const int wave = tid >> 6;
  const int lane = tid & 63;
  const int row0 = blockIdx.y * 128;
  const int col0 = blockIdx.x * 128;
  const int wr   = (wave >> 1) * 64;   // wave's output quadrant
  const int wc   = (wave & 1)  * 64;
  const int fr   = lane & 15;
  const int fq   = lane >> 4;

  f32x4 acc[4][4] = {};

  // staging: LDS byte o = j*4096 + wave*1024 + lane*16  ->  row = j*64 + (tid>>2), kelem = (tid&3)*8
  const int srow = tid >> 2;
  const int skof = (tid & 3) * 8;
  const unsigned short* gA = A + (size_t)(row0 + srow) * K + skof;
  const unsigned short* gB = B + (size_t)(col0 + srow) * K + skof;
  char* lA = (char*)&As[0][0] + wave * 1024;
  char* lB = (char*)&Bs[0][0] + wave * 1024;

  for (int k0 = 0; k0 < K; k0 += 32) {
    async_copy16(gA + k0,          lA);
    async_copy16(gA + k0 + 64 * K, lA + 4096);
    async_copy16(gB + k0,          lB);
    async_copy16(gB + k0 + 64 * K, lB + 4096);
    __syncthreads();   // drains vmcnt(0): tile resident

    bf16x8 af[4], bfr[4];
    #pragma unroll
    for (int i = 0; i < 4; ++i) {
      af[i]  = *(const bf16x8*)((const char*)&As[0][0] + (wr + i * 16 + fr) * 64 + fq * 16);
      bfr[i] = *(const bf16x8*)((const char*)&Bs[0][0] + (wc + i * 16 + fr) * 64 + fq * 16);
    }
    #pragma unroll
    for (int i = 0; i < 4; ++i)
      #pragma unroll
      for (int j = 0; j < 4; ++j)
        acc[i][j] = __builtin_amdgcn_mfma_f32_16x16x32_bf16(af[i], bfr[j], acc[i][j], 0, 0, 0);
    __syncthreads();   // all reads done before next stage overwrites
  }

  // C/D layout: col = lane&15, row = (lane>>4)*4 + reg
  #pragma unroll
  for (int i = 0; i < 4; ++i)
    #pragma unroll
    for (int j = 0; j < 4; ++j) {
      int row = row0 + wr + i * 16 + fq * 4;
      int col = col0 + wc + j * 16 + fr;
      #pragma unroll
      for (int r = 0; r < 4; ++r)
        C[(size_t)(row + r) * N + col] = acc[i][j][r];
    }
}

// ---------------------------------------------------------------------------
// Causal depthwise conv1d(K=4) + bias + SiLU.
// ---------------------------------------------------------------------------
__global__ __launch_bounds__(256) void conv_kernel(const float* __restrict__ xz,
                                                   const float* __restrict__ cw,
                                                   const float* __restrict__ cb,
                                                   float* __restrict__ u) {
  size_t idx = (size_t)blockIdx.x * 256 + threadIdx.x;
  int d = (int)(idx & (DINNER - 1));
  int t = (int)((idx >> 11) & (LSEQ - 1));
  const float4 w = *(const float4*)(cw + d * 4);
  float s = cb[d];
  size_t base = idx * 2 - (size_t)d;  // ((b*L+t)*2*DINNER + d)
  if (t >= 3) s += w.x * xz[base - 3 * (size_t)(2 * DINNER)];
  if (t >= 2) s += w.y * xz[base - 2 * (size_t)(2 * DINNER)];
  if (t >= 1) s += w.z * xz[base - 1 * (size_t)(2 * DINNER)];
  s += w.w * xz[base];
  float v = s / (1.0f + __expf(-s));
  u[idx] = v;
}

// ---------------------------------------------------------------------------
// x_dbl per (b,t) row: B,C -> bc; softplus-delta -> xi half of xz.
// ---------------------------------------------------------------------------
__global__ __launch_bounds__(256) void xdbl_kernel(const float* __restrict__ u,
                                                   const float* __restrict__ Wx,
                                                   const float* __restrict__ Wdt,
                                                   const float* __restrict__ bdt,
                                                   float* __restrict__ xz,
                                                   float* __restrict__ bc) {
  const int row = blockIdx.x;
  const int tid = threadIdx.x;
  __shared__ float sred[4][33];
  __shared__ float sdlt;

  float acc[33];
  #pragma unroll
  for (int e = 0; e < 33; ++e) acc[e] = 0.0f;

  const float* urow = u + (size_t)row * DINNER;
  for (int k = tid; k < DINNER; k += 256) {
    float uk = urow[k];
    #pragma unroll
    for (int e = 0; e < 33; ++e)
      acc[e] += uk * Wx[e * DINNER + k];
  }
  #pragma unroll
  for (int e = 0; e < 33; ++e) {
    #pragma unroll
    for (int m = 1; m < 64; m <<= 1)
      acc[e] += __shfl_xor(acc[e], m);
  }
  if ((tid & 63) == 0) {
    #pragma unroll
    for (int e = 0; e < 33; ++e) sred[tid >> 6][e] = acc[e];
  }
  __syncthreads();
  if (tid < 33) {
    float v = sred[0][tid] + sred[1][tid] + sred[2][tid] + sred[3][tid];
    if (tid == 0) sdlt = v;
    else          bc[(size_t)row * 32 + (tid - 1)] = v;
  }
  __syncthreads();
  const float dlt = sdlt;
  for (int d = tid; d < DINNER; d += 256) {
    float xarg = dlt * Wdt[d] + bdt[d];
    float sp = fmaxf(xarg, 0.0f) + log1pf(__expf(-fabsf(xarg)));
    xz[(size_t)row * (2 * DINNER) + d] = sp;
  }
}

// ---------------------------------------------------------------------------
// Chunked scan, phase A: per (channel-group, chunk) block, scan from h=0,
// emit P = prod(a_t), W = h_end.  Layout: ((gc*NCHUNK)+c)*16 + n
// ---------------------------------------------------------------------------
__global__ __launch_bounds__(256) void scanA(const float* __restrict__ u,
                                             const float* __restrict__ xz,
                                             const float* __restrict__ bc,
                                             const float* __restrict__ Amat,
                                             float* __restrict__ Pbuf,
                                             float* __restrict__ Wbuf) {
  __shared__ float su [LC][16];
  __shared__ float sdl[LC][16];
  __shared__ float sB [LC][16];
  const int tid = threadIdx.x;
  const int c   = blockIdx.x & (NCHUNK - 1);
  const int cg  = blockIdx.x >> 5;
  const int g   = tid >> 4;
  const int n   = tid & 15;
  const int gc  = cg * 16 + g;
  const int d   = gc & (DINNER - 1);
  const int d0  = (cg * 16) & (DINNER - 1);
  const int bb  = (cg * 16) >> 11;
  const int t0  = c * LC;

  #pragma unroll
  for (int i = 0; i < 4; ++i) {
    int idx = tid + i * 256;
    int tt = idx >> 4, dd = idx & 15;
    size_t grow = (size_t)bb * LSEQ + t0 + tt;
    su [tt][dd] = u [grow * DINNER + d0 + dd];
    sdl[tt][dd] = xz[grow * (2 * DINNER) + d0 + dd];
    sB [tt][dd] = bc[grow * 32 + dd];
  }
  __syncthreads();

  const float A_dn = Amat[d * NST + n];
  float P = 1.0f, h = 0.0f;
  #pragma unroll 8
  for (int tt = 0; tt < LC; ++tt) {
    float dl = sdl[tt][g];
    float uu = su [tt][g];
    float Bn = sB [tt][n];
    float ab = __expf(dl * A_dn);
    h = ab * h + (dl * uu) * Bn;
    P *= ab;
  }
  size_t o = ((size_t)gc * NCHUNK + c) * 16 + n;
  Pbuf[o] = P;
  Wbuf[o] = h;
}

// ---------------------------------------------------------------------------
// Phase B: combine 32 chunk summaries per (b,d,n) lane; Hin over Pbuf.
// ---------------------------------------------------------------------------
__global__ __launch_bounds__(256) void scanB(float* __restrict__ Pbuf,
                                             const float* __restrict__ Wbuf) {
  const int lane_id = blockIdx.x * 256 + threadIdx.x;
  const int gc = lane_id >> 4;
  const int n  = lane_id & 15;
  const size_t base = (size_t)gc * NCHUNK * 16 + n;
  float P[NCHUNK], W[NCHUNK];
  #pragma unroll
  for (int c = 0; c < NCHUNK; ++c) {
    P[c] = Pbuf[base + (size_t)c * 16];
    W[c] = Wbuf[base + (size_t)c * 16];
  }
  float h = 0.0f;
  #pragma unroll
  for (int c = 0; c < NCHUNK; ++c) {
    float hin = h;
    h = P[c] * h + W[c];
    Pbuf[base + (size_t)c * 16] = hin;
  }
}

// ---------------------------------------------------------------------------
// Phase C: rescan from Hin, reduce over n, SiLU(z) gate, y (fp32) over u.
// ---------------------------------------------------------------------------
__global__ __launch_bounds__(256) void scanC(float* __restrict__ u,
                                             const float* __restrict__ xz,
                                             const float* __restrict__ bc,
                                             const float* __restrict__ Amat,
                                             const float* __restrict__ Hin) {
  __shared__ float su [LC][16];
  __shared__ float sdl[LC][16];
  __shared__ float szg[LC][16];
  __shared__ float sB [LC][16];
  __shared__ float sC [LC][16];
  const int tid = threadIdx.x;
  const int c   = blockIdx.x & (NCHUNK - 1);
  const int cg  = blockIdx.x >> 5;
  const int g   = tid >> 4;
  const int n   = tid & 15;
  const int gc  = cg * 16 + g;
  const int d   = gc & (DINNER - 1);
  const int d0  = (cg * 16) & (DINNER - 1);
  const int bb  = (cg * 16) >> 11;
  const int t0  = c * LC;

  #pragma unroll
  for (int i = 0; i < 4; ++i) {
    int idx = tid + i * 256;
    int tt = idx >> 4, dd = idx & 15;
    size_t grow = (size_t)bb * LSEQ + t0 + tt;
    su [tt][dd] = u [grow * DINNER + d0 + dd];
    sdl[tt][dd] = xz[grow * (2 * DINNER) + d0 + dd];
    szg[tt][dd] = xz[grow * (2 * DINNER) + DINNER + d0 + dd];
  }
  #pragma unroll
  for (int i = 0; i < 8; ++i) {
    int idx = tid + i * 256;
    int tt = idx >> 5, e = idx & 31;
    float v = bc[((size_t)bb * LSEQ + t0 + tt) * 32 + e];
    if (e < 16) sB[tt][e] = v;
    else        sC[tt][e - 16] = v;
  }
  __syncthreads();

  const float A_dn = Amat[d * NST + n];
  float h = Hin[((size_t)gc * NCHUNK + c) * 16 + n];
  #pragma unroll 8
  for (int tt = 0; tt < LC; ++tt) {
    float dl = sdl[tt][g];
    float uu = su [tt][g];
    float zt = szg[tt][g];
    float Bn = sB [tt][n];
    float Cn = sC [tt][n];
    float ab = __expf(dl * A_dn);
    h = ab * h + (dl * uu) * Bn;
    float p = h * Cn;
    p += __shfl_xor(p, 1);
    p += __shfl_xor(p, 2);
    p += __shfl_xor(p, 4);
    p += __shfl_xor(p, 8);
    if (n == 0) {
      float sig = 1.0f / (1.0f + __expf(-zt));
      u[((size_t)bb * LSEQ + t0 + tt) * DINNER + d] = p * zt * sig;
    }
  }
}

// ---------------------------------------------------------------------------
extern "C" void kernel_launch(void* const* d_in, const int* in_sizes, int n_in,
                              void* d_out, int out_size, void* d_ws, size_t ws_size,
                              hipStream_t stream) {
  const float* x      = (const float*)d_in[0];
  const float* W_in   = (const float*)d_in[1];
  const float* conv_w = (const float*)d_in[2];
  const float* conv_b = (const float*)d_in[3];
  const float* A      = (const float*)d_in[4];
  const float* W_x    = (const float*)d_in[5];
  const float* W_dt   = (const float*)d_in[6];
  const float* b_dt   = (const float*)d_in[7];
  const float* W_out  = (const float*)d_in[8];
  float* out = (float*)d_out;

  float* ws = (float*)d_ws;
  float* xz = ws;                                        // (B*L, 4096)   64 MB
  float* u  = xz + (size_t)BATCH * LSEQ * 2 * DINNER;    // (B*L, 2048)   32 MB
  float* bc = u  + (size_t)BATCH * LSEQ * DINNER;        // (B*L, 32)    0.5 MB
  float* Pb = bc + (size_t)BATCH * LSEQ * 32;            // 2M floats      8 MB
  float* Wb = Pb + (size_t)BATCH * DINNER * NCHUNK * 16; // 2M floats      8 MB

  const int ML = BATCH * LSEQ;  // 4096

  // bf16 aliases (regions dead at time of use)
  unsigned short* x_bf   = (unsigned short*)Pb;   // 4M bf16 = 8 MB (dead until scanA)
  unsigned short* win_bf = (unsigned short*)Wb;   // 4M bf16 = 8 MB (dead until scanA)
  unsigned short* y_bf   = (unsigned short*)Pb;   // 8M bf16 = 16 MB spans Pb+Wb (dead after scanC)
  unsigned short* wout_bf= (unsigned short*)xz;   // 2M bf16 = 4 MB (xz dead after scanC)

  // 0) convert in_proj operands to bf16
  cvt_bf16<<<(ML * DMODEL / 4) / 256, 256, 0, stream>>>((const float4*)x,    (ushort4*)x_bf,   ML * DMODEL / 4);
  cvt_bf16<<<(2 * DINNER * DMODEL / 4) / 256, 256, 0, stream>>>((const float4*)W_in, (ushort4*)win_bf, 2 * DINNER * DMODEL / 4);
  // 1) in_proj (bf16 MFMA)
  gemm_bf16<2 * DINNER, DMODEL><<<dim3((2 * DINNER) / 128, ML / 128), 256, 0, stream>>>(x_bf, win_bf, xz);
  // 2) conv + silu
  conv_kernel<<<(ML * DINNER) / 256, 256, 0, stream>>>(xz, conv_w, conv_b, u);
  // 3) x_dbl
  xdbl_kernel<<<ML, 256, 0, stream>>>(u, W_x, W_dt, b_dt, xz, bc);
  // 4) chunked selective scan
  scanA<<<(BATCH * DINNER / 16) * NCHUNK, 256, 0, stream>>>(u, xz, bc, A, Pb, Wb);
  scanB<<<(BATCH * DINNER * NST) / 256, 256, 0, stream>>>(Pb, Wb);
  scanC<<<(BATCH * DINNER / 16) * NCHUNK, 256, 0, stream>>>(u, xz, bc, A, Pb);
  // 5) convert out_proj operands, then out_proj (bf16 MFMA)
  cvt_bf16<<<(ML * DINNER / 4) / 256, 256, 0, stream>>>((const float4*)u,     (ushort4*)y_bf,    ML * DINNER / 4);
  cvt_bf16<<<(DMODEL * DINNER / 4) / 256, 256, 0, stream>>>((const float4*)W_out, (ushort4*)wout_bf, DMODEL * DINNER / 4);
  gemm_bf16<DMODEL, DINNER><<<dim3(DMODEL / 128, ML / 128), 256, 0, stream>>>(y_bf, wout_bf, out);
}

// Round 4
// 335.475 us; speedup vs baseline: 3.8421x; 1.1249x over previous
//
#include <hip/hip_runtime.h>
#include <hip/hip_bf16.h>

// Problem constants
#define BATCH   2
#define LSEQ    2048
#define DMODEL  1024
#define DINNER  2048
#define NST     16

// Chunked scan parameters
#define LC      64
#define NCHUNK  (LSEQ / LC)   // 32

#define LOG2E 1.4426950408889634f

typedef __bf16 bf16x8 __attribute__((ext_vector_type(8)));
typedef float  f32x4  __attribute__((ext_vector_type(4)));

// float -> bf16 round-to-nearest-even (inputs are finite; skip NaN path)
__device__ __forceinline__ unsigned short f2bf(float f) {
  unsigned int u = __float_as_uint(f);
  return (unsigned short)((u + 0x7FFFu + ((u >> 16) & 1u)) >> 16);
}

__device__ __forceinline__ void async_copy16(const void* g, void* l) {
  __builtin_amdgcn_global_load_lds((__attribute__((address_space(1))) void*)g,
                                   (__attribute__((address_space(3))) void*)l,
                                   16, 0, 0);
}

// ---------------------------------------------------------------------------
// f32 -> bf16 conversion, 4 elements/thread
// ---------------------------------------------------------------------------
__global__ __launch_bounds__(256) void cvt_bf16(const float4* __restrict__ in,
                                                ushort4* __restrict__ o, int n4) {
  int i = blockIdx.x * 256 + threadIdx.x;
  if (i >= n4) return;
  float4 v = in[i];
  ushort4 r;
  r.x = f2bf(v.x); r.y = f2bf(v.y); r.z = f2bf(v.z); r.w = f2bf(v.w);
  o[i] = r;
}

// ---------------------------------------------------------------------------
// bf16 NT GEMM (m97 structure): C[m][n] = sum_k A[m][k]*B[n][k], C fp32.
// ---------------------------------------------------------------------------
template<int N, int K>
__global__ __launch_bounds__(256, 2) void gemm_bf16(const unsigned short* __restrict__ A,
                                                    const unsigned short* __restrict__ B,
                                                    float* __restrict__ C) {
  __shared__ unsigned short As[128][32];
  __shared__ unsigned short Bs[128][32];
  const int tid  = threadIdx.x;
  const int wave = tid >> 6;
  const int lane = tid & 63;
  const int row0 = blockIdx.y * 128;
  const int col0 = blockIdx.x * 128;
  const int wr   = (wave >> 1) * 64;
  const int wc   = (wave & 1)  * 64;
  const int fr   = lane & 15;
  const int fq   = lane >> 4;

  f32x4 acc[4][4] = {};

  const int srow = tid >> 2;
  const int skof = (tid & 3) * 8;
  const unsigned short* gA = A + (size_t)(row0 + srow) * K + skof;
  const unsigned short* gB = B + (size_t)(col0 + srow) * K + skof;
  char* lA = (char*)&As[0][0] + wave * 1024;
  char* lB = (char*)&Bs[0][0] + wave * 1024;

  for (int k0 = 0; k0 < K; k0 += 32) {
    async_copy16(gA + k0,          lA);
    async_copy16(gA + k0 + 64 * K, lA + 4096);
    async_copy16(gB + k0,          lB);
    async_copy16(gB + k0 + 64 * K, lB + 4096);
    __syncthreads();

    bf16x8 af[4], bfr[4];
    #pragma unroll
    for (int i = 0; i < 4; ++i) {
      af[i]  = *(const bf16x8*)((const char*)&As[0][0] + (wr + i * 16 + fr) * 64 + fq * 16);
      bfr[i] = *(const bf16x8*)((const char*)&Bs[0][0] + (wc + i * 16 + fr) * 64 + fq * 16);
    }
    #pragma unroll
    for (int i = 0; i < 4; ++i)
      #pragma unroll
      for (int j = 0; j < 4; ++j)
        acc[i][j] = __builtin_amdgcn_mfma_f32_16x16x32_bf16(af[i], bfr[j], acc[i][j], 0, 0, 0);
    __syncthreads();
  }

  #pragma unroll
  for (int i = 0; i < 4; ++i)
    #pragma unroll
    for (int j = 0; j < 4; ++j) {
      int row = row0 + wr + i * 16 + fq * 4;
      int col = col0 + wc + j * 16 + fr;
      #pragma unroll
      for (int r = 0; r < 4; ++r)
        C[(size_t)(row + r) * N + col] = acc[i][j][r];
    }
}

// ---------------------------------------------------------------------------
// Causal depthwise conv1d(K=4) + bias + SiLU.
// ---------------------------------------------------------------------------
__global__ __launch_bounds__(256) void conv_kernel(const float* __restrict__ xz,
                                                   const float* __restrict__ cw,
                                                   const float* __restrict__ cb,
                                                   float* __restrict__ u) {
  size_t idx = (size_t)blockIdx.x * 256 + threadIdx.x;
  int d = (int)(idx & (DINNER - 1));
  int t = (int)((idx >> 11) & (LSEQ - 1));
  const float4 w = *(const float4*)(cw + d * 4);
  float s = cb[d];
  size_t base = idx * 2 - (size_t)d;
  if (t >= 3) s += w.x * xz[base - 3 * (size_t)(2 * DINNER)];
  if (t >= 2) s += w.y * xz[base - 2 * (size_t)(2 * DINNER)];
  if (t >= 1) s += w.z * xz[base - 1 * (size_t)(2 * DINNER)];
  s += w.w * xz[base];
  float v = s / (1.0f + __expf(-s));
  u[idx] = v;
}

// ---------------------------------------------------------------------------
// x_dbl per (b,t) row: B,C -> bc; softplus-delta -> xi half of xz.
// ---------------------------------------------------------------------------
__global__ __launch_bounds__(256) void xdbl_kernel(const float* __restrict__ u,
                                                   const float* __restrict__ Wx,
                                                   const float* __restrict__ Wdt,
                                                   const float* __restrict__ bdt,
                                                   float* __restrict__ xz,
                                                   float* __restrict__ bc) {
  const int row = blockIdx.x;
  const int tid = threadIdx.x;
  __shared__ float sred[4][33];
  __shared__ float sdlt;

  float acc[33];
  #pragma unroll
  for (int e = 0; e < 33; ++e) acc[e] = 0.0f;

  const float* urow = u + (size_t)row * DINNER;
  for (int k = tid; k < DINNER; k += 256) {
    float uk = urow[k];
    #pragma unroll
    for (int e = 0; e < 33; ++e)
      acc[e] += uk * Wx[e * DINNER + k];
  }
  #pragma unroll
  for (int e = 0; e < 33; ++e) {
    #pragma unroll
    for (int m = 1; m < 64; m <<= 1)
      acc[e] += __shfl_xor(acc[e], m);
  }
  if ((tid & 63) == 0) {
    #pragma unroll
    for (int e = 0; e < 33; ++e) sred[tid >> 6][e] = acc[e];
  }
  __syncthreads();
  if (tid < 33) {
    float v = sred[0][tid] + sred[1][tid] + sred[2][tid] + sred[3][tid];
    if (tid == 0) sdlt = v;
    else          bc[(size_t)row * 32 + (tid - 1)] = v;
  }
  __syncthreads();
  const float dlt = sdlt;
  for (int d = tid; d < DINNER; d += 256) {
    float xarg = dlt * Wdt[d] + bdt[d];
    float sp = fmaxf(xarg, 0.0f) + log1pf(__expf(-fabsf(xarg)));
    xz[(size_t)row * (2 * DINNER) + d] = sp;
  }
}

// ---------------------------------------------------------------------------
// Chunked scan, phase A. Lane = one (b, d, chunk); all 16 states in regs.
// Emits P_n = exp2(A2_n * S) (S = sum dl over chunk), W_n = h_end.
// Layout: ((b*DINNER+d)*NCHUNK + c)*16 + n
// blockIdx.x = b*(NCHUNK*8) + c*8 + dblk   (DINNER/256 = 8)
// ---------------------------------------------------------------------------
__global__ __launch_bounds__(256) void scanA(const float* __restrict__ u,
                                             const float* __restrict__ xz,
                                             const float* __restrict__ bc,
                                             const float* __restrict__ Amat,
                                             float* __restrict__ Pbuf,
                                             float* __restrict__ Wbuf) {
  const int tid  = threadIdx.x;
  const int dblk = blockIdx.x & 7;
  const int c    = (blockIdx.x >> 3) & (NCHUNK - 1);
  const int b    = blockIdx.x >> 8;
  const int d    = dblk * 256 + tid;
  const int t0   = c * LC;

  float A2[16];   // A * log2(e), so exp(dl*A) = exp2(dl*A2)
  #pragma unroll
  for (int i = 0; i < 4; ++i) {
    float4 v = *(const float4*)(Amat + (size_t)d * 16 + i * 4);
    A2[i*4+0] = v.x * LOG2E; A2[i*4+1] = v.y * LOG2E;
    A2[i*4+2] = v.z * LOG2E; A2[i*4+3] = v.w * LOG2E;
  }
  float h[16];
  #pragma unroll
  for (int n = 0; n < 16; ++n) h[n] = 0.0f;
  float S = 0.0f;

  const float* bcb = bc + ((size_t)b * LSEQ + t0) * 32;
  size_t gu = ((size_t)b * LSEQ + t0) * DINNER + d;
  size_t gx = ((size_t)b * LSEQ + t0) * (2 * DINNER) + d;

  float u_c = u[gu], dl_c = xz[gx];
  for (int tt = 0; tt < LC; ++tt) {
    // prefetch next t (last iter reads 1 row past chunk: stays inside d_ws, unused)
    float u_n  = u [gu + DINNER];
    float dl_n = xz[gx + 2 * DINNER];
    gu += DINNER; gx += 2 * DINNER;
    float4 B0 = *(const float4*)(bcb + tt * 32 + 0);
    float4 B1 = *(const float4*)(bcb + tt * 32 + 4);
    float4 B2 = *(const float4*)(bcb + tt * 32 + 8);
    float4 B3 = *(const float4*)(bcb + tt * 32 + 12);
    float Bv[16] = {B0.x,B0.y,B0.z,B0.w, B1.x,B1.y,B1.z,B1.w,
                    B2.x,B2.y,B2.z,B2.w, B3.x,B3.y,B3.z,B3.w};
    S += dl_c;
    float dlu = dl_c * u_c;
    #pragma unroll
    for (int n = 0; n < 16; ++n) {
      float ab = exp2f(dl_c * A2[n]);
      h[n] = fmaf(ab, h[n], dlu * Bv[n]);
    }
    u_c = u_n; dl_c = dl_n;
  }

  size_t o = ((size_t)(b * DINNER + d) * NCHUNK + c) * 16;
  float P[16];
  #pragma unroll
  for (int n = 0; n < 16; ++n) P[n] = exp2f(A2[n] * S);
  #pragma unroll
  for (int i = 0; i < 4; ++i) {
    *(float4*)(Pbuf + o + i * 4) = make_float4(P[i*4], P[i*4+1], P[i*4+2], P[i*4+3]);
    *(float4*)(Wbuf + o + i * 4) = make_float4(h[i*4], h[i*4+1], h[i*4+2], h[i*4+3]);
  }
}

// ---------------------------------------------------------------------------
// Phase B: combine 32 chunk summaries per (b,d,n) lane; Hin over Pbuf.
// ---------------------------------------------------------------------------
__global__ __launch_bounds__(256) void scanB(float* __restrict__ Pbuf,
                                             const float* __restrict__ Wbuf) {
  const int lane_id = blockIdx.x * 256 + threadIdx.x;
  const int gc = lane_id >> 4;
  const int n  = lane_id & 15;
  const size_t base = (size_t)gc * NCHUNK * 16 + n;
  float P[NCHUNK], W[NCHUNK];
  #pragma unroll
  for (int c = 0; c < NCHUNK; ++c) {
    P[c] = Pbuf[base + (size_t)c * 16];
    W[c] = Wbuf[base + (size_t)c * 16];
  }
  float h = 0.0f;
  #pragma unroll
  for (int c = 0; c < NCHUNK; ++c) {
    float hin = h;
    h = P[c] * h + W[c];
    Pbuf[base + (size_t)c * 16] = hin;
  }
}

// ---------------------------------------------------------------------------
// Phase C: lane = one (b, d, chunk); start from Hin, rescan, y = sum_n h_n C_n,
// SiLU(z) gate, write y (fp32) in place over u.
// ---------------------------------------------------------------------------
__global__ __launch_bounds__(256) void scanC(float* __restrict__ u,
                                             const float* __restrict__ xz,
                                             const float* __restrict__ bc,
                                             const float* __restrict__ Amat,
                                             const float* __restrict__ Hin) {
  const int tid  = threadIdx.x;
  const int dblk = blockIdx.x & 7;
  const int c    = (blockIdx.x >> 3) & (NCHUNK - 1);
  const int b    = blockIdx.x >> 8;
  const int d    = dblk * 256 + tid;
  const int t0   = c * LC;

  float A2[16];
  #pragma unroll
  for (int i = 0; i < 4; ++i) {
    float4 v = *(const float4*)(Amat + (size_t)d * 16 + i * 4);
    A2[i*4+0] = v.x * LOG2E; A2[i*4+1] = v.y * LOG2E;
    A2[i*4+2] = v.z * LOG2E; A2[i*4+3] = v.w * LOG2E;
  }
  const size_t o = ((size_t)(b * DINNER + d) * NCHUNK + c) * 16;
  float h[16];
  #pragma unroll
  for (int i = 0; i < 4; ++i) {
    float4 v = *(const float4*)(Hin + o + i * 4);
    h[i*4+0] = v.x; h[i*4+1] = v.y; h[i*4+2] = v.z; h[i*4+3] = v.w;
  }

  const float* bcb = bc + ((size_t)b * LSEQ + t0) * 32;
  size_t gu = ((size_t)b * LSEQ + t0) * DINNER + d;
  size_t gx = ((size_t)b * LSEQ + t0) * (2 * DINNER) + d;

  float u_c = u[gu], dl_c = xz[gx], z_c = xz[gx + DINNER];
  for (int tt = 0; tt < LC; ++tt) {
    size_t cu = gu;
    gu += DINNER; gx += 2 * DINNER;
    float u_n  = u [gu];
    float dl_n = xz[gx];
    float z_n  = xz[gx + DINNER];
    float4 B0 = *(const float4*)(bcb + tt * 32 + 0);
    float4 B1 = *(const float4*)(bcb + tt * 32 + 4);
    float4 B2 = *(const float4*)(bcb + tt * 32 + 8);
    float4 B3 = *(const float4*)(bcb + tt * 32 + 12);
    float4 C0 = *(const float4*)(bcb + tt * 32 + 16);
    float4 C1 = *(const float4*)(bcb + tt * 32 + 20);
    float4 C2 = *(const float4*)(bcb + tt * 32 + 24);
    float4 C3 = *(const float4*)(bcb + tt * 32 + 28);
    float Bv[16] = {B0.x,B0.y,B0.z,B0.w, B1.x,B1.y,B1.z,B1.w,
                    B2.x,B2.y,B2.z,B2.w, B3.x,B3.y,B3.z,B3.w};
    float Cv[16] = {C0.x,C0.y,C0.z,C0.w, C1.x,C1.y,C1.z,C1.w,
                    C2.x,C2.y,C2.z,C2.w, C3.x,C3.y,C3.z,C3.w};
    float dlu = dl_c * u_c;
    float y = 0.0f;
    #pragma unroll
    for (int n = 0; n < 16; ++n) {
      float ab = exp2f(dl_c * A2[n]);
      h[n] = fmaf(ab, h[n], dlu * Bv[n]);
      y = fmaf(h[n], Cv[n], y);
    }
    float sig = 1.0f / (1.0f + __expf(-z_c));
    u[cu] = y * z_c * sig;   // in place over u (same element, same lane)
    u_c = u_n; dl_c = dl_n; z_c = z_n;
  }
}

// ---------------------------------------------------------------------------
extern "C" void kernel_launch(void* const* d_in, const int* in_sizes, int n_in,
                              void* d_out, int out_size, void* d_ws, size_t ws_size,
                              hipStream_t stream) {
  const float* x      = (const float*)d_in[0];
  const float* W_in   = (const float*)d_in[1];
  const float* conv_w = (const float*)d_in[2];
  const float* conv_b = (const float*)d_in[3];
  const float* A      = (const float*)d_in[4];
  const float* W_x    = (const float*)d_in[5];
  const float* W_dt   = (const float*)d_in[6];
  const float* b_dt   = (const float*)d_in[7];
  const float* W_out  = (const float*)d_in[8];
  float* out = (float*)d_out;

  float* ws = (float*)d_ws;
  float* xz = ws;                                        // (B*L, 4096)   64 MB
  float* u  = xz + (size_t)BATCH * LSEQ * 2 * DINNER;    // (B*L, 2048)   32 MB
  float* bc = u  + (size_t)BATCH * LSEQ * DINNER;        // (B*L, 32)    0.5 MB
  float* Pb = bc + (size_t)BATCH * LSEQ * 32;            // 2M floats      8 MB
  float* Wb = Pb + (size_t)BATCH * DINNER * NCHUNK * 16; // 2M floats      8 MB

  const int ML = BATCH * LSEQ;  // 4096

  // bf16 aliases (regions dead at time of use)
  unsigned short* x_bf    = (unsigned short*)Pb;   // dead until scanA
  unsigned short* win_bf  = (unsigned short*)Wb;   // dead until scanA
  unsigned short* y_bf    = (unsigned short*)Pb;   // spans Pb+Wb, dead after scanC
  unsigned short* wout_bf = (unsigned short*)xz;   // xz dead after scanC

  // 0) convert in_proj operands to bf16
  cvt_bf16<<<(ML * DMODEL / 4) / 256, 256, 0, stream>>>((const float4*)x,    (ushort4*)x_bf,   ML * DMODEL / 4);
  cvt_bf16<<<(2 * DINNER * DMODEL / 4) / 256, 256, 0, stream>>>((const float4*)W_in, (ushort4*)win_bf, 2 * DINNER * DMODEL / 4);
  // 1) in_proj (bf16 MFMA)
  gemm_bf16<2 * DINNER, DMODEL><<<dim3((2 * DINNER) / 128, ML / 128), 256, 0, stream>>>(x_bf, win_bf, xz);
  // 2) conv + silu
  conv_kernel<<<(ML * DINNER) / 256, 256, 0, stream>>>(xz, conv_w, conv_b, u);
  // 3) x_dbl
  xdbl_kernel<<<ML, 256, 0, stream>>>(u, W_x, W_dt, b_dt, xz, bc);
  // 4) chunked selective scan (register-state lanes)
  scanA<<<BATCH * NCHUNK * 8, 256, 0, stream>>>(u, xz, bc, A, Pb, Wb);
  scanB<<<(BATCH * DINNER * NST) / 256, 256, 0, stream>>>(Pb, Wb);
  scanC<<<BATCH * NCHUNK * 8, 256, 0, stream>>>(u, xz, bc, A, Pb);
  // 5) convert out_proj operands, then out_proj (bf16 MFMA)
  cvt_bf16<<<(ML * DINNER / 4) / 256, 256, 0, stream>>>((const float4*)u,     (ushort4*)y_bf,    ML * DINNER / 4);
  cvt_bf16<<<(DMODEL * DINNER / 4) / 256, 256, 0, stream>>>((const float4*)W_out, (ushort4*)wout_bf, DMODEL * DINNER / 4);
  gemm_bf16<DMODEL, DINNER><<<dim3(DMODEL / 128, ML / 128), 256, 0, stream>>>(y_bf, wout_bf, out);
}